// Round 1
// baseline (22002.725 us; speedup 1.0000x reference)
//
#include <hip/hip_runtime.h>
#include <hip/hip_bf16.h>
#include <math.h>

#define BB 4
#define TT 1024
#define DD 1024
#define HH 16
#define HDIM 64
#define FFD 4096
#define VV 32000
#define LL 6
#define BT (BB * TT)

// ---------------- embedding: x = tok_emb[idx] + pos_emb ----------------
__global__ __launch_bounds__(256) void embed_k(const int* __restrict__ idx,
                                               const float* __restrict__ tok,
                                               const float* __restrict__ pos,
                                               float* __restrict__ x) {
    int row = blockIdx.x;          // b*T + t
    int tid = threadIdx.x;         // 256 threads * 4 floats = 1024 = D
    int t = row & (TT - 1);
    int token = idx[row];
    float4 a = *(const float4*)(tok + (size_t)token * DD + tid * 4);
    float4 p = *(const float4*)(pos + (size_t)t * DD + tid * 4);
    float4 o = make_float4(a.x + p.x, a.y + p.y, a.z + p.z, a.w + p.w);
    *(float4*)(x + (size_t)row * DD + tid * 4) = o;
}

// ---------------- layernorm: one block per row (D=1024) ----------------
__global__ __launch_bounds__(256) void layernorm_k(const float* __restrict__ in,
                                                   float* __restrict__ out,
                                                   const float* __restrict__ g,
                                                   const float* __restrict__ b) {
    __shared__ float red[256];
    int row = blockIdx.x;
    int tid = threadIdx.x;
    const float* ip = in + (size_t)row * DD;
    float4 v = *(const float4*)(ip + tid * 4);

    float s = v.x + v.y + v.z + v.w;
    red[tid] = s; __syncthreads();
    for (int st = 128; st > 0; st >>= 1) { if (tid < st) red[tid] += red[tid + st]; __syncthreads(); }
    float mu = red[0] * (1.0f / DD);
    __syncthreads();

    float d0 = v.x - mu, d1 = v.y - mu, d2 = v.z - mu, d3 = v.w - mu;
    red[tid] = d0 * d0 + d1 * d1 + d2 * d2 + d3 * d3; __syncthreads();
    for (int st = 128; st > 0; st >>= 1) { if (tid < st) red[tid] += red[tid + st]; __syncthreads(); }
    float var = red[0] * (1.0f / DD);
    float rs = rsqrtf(var + 1e-5f);

    float4 gv = *(const float4*)(g + tid * 4);
    float4 bv = *(const float4*)(b + tid * 4);
    float4 o = make_float4(d0 * rs * gv.x + bv.x, d1 * rs * gv.y + bv.y,
                           d2 * rs * gv.z + bv.z, d3 * rs * gv.w + bv.w);
    *(float4*)(out + (size_t)row * DD + tid * 4) = o;
}

// ---------------- generic f32 GEMM: C[M,N] (=/+=) A[M,K] * W[N,K]^T ----------------
// 64x64 tile, BK=16, 256 threads, 4x4 per thread.
template <bool ADD, bool BIAS, bool GELU>
__global__ __launch_bounds__(256) void gemm_bt(const float* __restrict__ A,
                                               const float* __restrict__ W,
                                               const float* __restrict__ bias,
                                               float* __restrict__ C,
                                               int M, int N, int K) {
    __shared__ float As[16][64];
    __shared__ float Ws[16][64];
    const int tid = threadIdx.x;
    const int tx = tid & 15, ty = tid >> 4;
    const int m0 = blockIdx.y * 64, n0 = blockIdx.x * 64;
    const int lrow = tid >> 2;            // 0..63
    const int lk4 = (tid & 3) * 4;        // 0,4,8,12

    float acc[4][4] = {};

    for (int k0 = 0; k0 < K; k0 += 16) {
        float4 av = *(const float4*)(A + (size_t)(m0 + lrow) * K + k0 + lk4);
        float4 wv = *(const float4*)(W + (size_t)(n0 + lrow) * K + k0 + lk4);
        As[lk4 + 0][lrow] = av.x; As[lk4 + 1][lrow] = av.y;
        As[lk4 + 2][lrow] = av.z; As[lk4 + 3][lrow] = av.w;
        Ws[lk4 + 0][lrow] = wv.x; Ws[lk4 + 1][lrow] = wv.y;
        Ws[lk4 + 2][lrow] = wv.z; Ws[lk4 + 3][lrow] = wv.w;
        __syncthreads();
#pragma unroll
        for (int k = 0; k < 16; ++k) {
            float4 a = *(const float4*)&As[k][ty * 4];
            float4 w = *(const float4*)&Ws[k][tx * 4];
            acc[0][0] += a.x * w.x; acc[0][1] += a.x * w.y; acc[0][2] += a.x * w.z; acc[0][3] += a.x * w.w;
            acc[1][0] += a.y * w.x; acc[1][1] += a.y * w.y; acc[1][2] += a.y * w.z; acc[1][3] += a.y * w.w;
            acc[2][0] += a.z * w.x; acc[2][1] += a.z * w.y; acc[2][2] += a.z * w.z; acc[2][3] += a.z * w.w;
            acc[3][0] += a.w * w.x; acc[3][1] += a.w * w.y; acc[3][2] += a.w * w.z; acc[3][3] += a.w * w.w;
        }
        __syncthreads();
    }

#pragma unroll
    for (int i = 0; i < 4; ++i) {
        int m = m0 + ty * 4 + i;
#pragma unroll
        for (int j = 0; j < 4; ++j) {
            int n = n0 + tx * 4 + j;
            float v = acc[i][j];
            if (BIAS) v += bias[n];
            if (GELU) v = 0.5f * v * (1.0f + erff(v * 0.70710678118654752f));
            float* p = C + (size_t)m * N + n;
            if (ADD) *p += v; else *p = v;
        }
    }
}

// ---------------- attention: one block per (b, h, q) ----------------
// qkv layout: [B, T, 3*D]; head h occupies cols h*64..h*64+63 within each D block.
__global__ __launch_bounds__(256) void attn_k(const float* __restrict__ qkv,
                                              float* __restrict__ y) {
    __shared__ float sc[TT];
    __shared__ float qv[HDIM];
    __shared__ float red[256];
    const int bid = blockIdx.x;
    const int q = bid & (TT - 1);
    const int h = (bid >> 10) & (HH - 1);
    const int b = bid >> 14;
    const int tid = threadIdx.x;
    const size_t rstr = 3 * DD;
    const float* base = qkv + (size_t)b * TT * rstr;

    if (tid < HDIM) qv[tid] = base[(size_t)q * rstr + h * HDIM + tid];
    __syncthreads();

    // scores s[k] = q . k / 8 for k <= q
    const float* kp = base + DD + h * HDIM;
    for (int k = tid; k <= q; k += 256) {
        const float* kr = kp + (size_t)k * rstr;
        float s = 0.f;
#pragma unroll 8
        for (int d = 0; d < HDIM; ++d) s += qv[d] * kr[d];
        sc[k] = s * 0.125f;
    }

    // max reduce
    float lm = -1e30f;
    for (int k = tid; k <= q; k += 256) lm = fmaxf(lm, sc[k]);
    red[tid] = lm; __syncthreads();
    for (int st = 128; st > 0; st >>= 1) { if (tid < st) red[tid] = fmaxf(red[tid], red[tid + st]); __syncthreads(); }
    float mx = red[0]; __syncthreads();

    // exp + sum
    float ls = 0.f;
    for (int k = tid; k <= q; k += 256) { float e = __expf(sc[k] - mx); sc[k] = e; ls += e; }
    red[tid] = ls; __syncthreads();
    for (int st = 128; st > 0; st >>= 1) { if (tid < st) red[tid] += red[tid + st]; __syncthreads(); }
    float inv = 1.0f / red[0]; __syncthreads();

    // PV: 4 groups of 64 threads; group g handles keys k = g, g+4, ...
    const int g = tid >> 6, d = tid & 63;
    const float* vp = base + 2 * DD + h * HDIM + d;
    float part = 0.f;
    for (int k = g; k <= q; k += 4) part += sc[k] * vp[(size_t)k * rstr];
    red[tid] = part; __syncthreads();
    if (tid < 64) {
        float yv = (red[d] + red[64 + d] + red[128 + d] + red[192 + d]) * inv;
        y[(size_t)(b * TT + q) * DD + h * HDIM + d] = yv;
    }
}

// ---------------- host ----------------
extern "C" void kernel_launch(void* const* d_in, const int* in_sizes, int n_in,
                              void* d_out, int out_size, void* d_ws, size_t ws_size,
                              hipStream_t stream) {
    const int*   idx     = (const int*)d_in[0];
    const float* tok_emb = (const float*)d_in[1];
    const float* pos_emb = (const float*)d_in[2];
    const float* ln1_g   = (const float*)d_in[3];
    const float* ln1_b   = (const float*)d_in[4];
    const float* qkv_w   = (const float*)d_in[5];
    const float* proj_w  = (const float*)d_in[6];
    const float* ln2_g   = (const float*)d_in[7];
    const float* ln2_b   = (const float*)d_in[8];
    const float* mlp_w1  = (const float*)d_in[9];
    const float* mlp_b1  = (const float*)d_in[10];
    const float* mlp_w2  = (const float*)d_in[11];
    const float* mlp_b2  = (const float*)d_in[12];
    const float* lnf_g   = (const float*)d_in[13];
    const float* lnf_b   = (const float*)d_in[14];
    const float* head_w  = (const float*)d_in[15];
    float* out = (float*)d_out;

    // workspace layout (f32): x[BT*D], h[BT*D], qkv[BT*3D], ff[BT*FF]  ~151 MB
    float* x    = (float*)d_ws;
    float* hb   = x    + (size_t)BT * DD;
    float* qkvb = hb   + (size_t)BT * DD;
    float* ffb  = qkvb + (size_t)BT * 3 * DD;

    embed_k<<<BT, 256, 0, stream>>>(idx, tok_emb, pos_emb, x);

    for (int l = 0; l < LL; ++l) {
        layernorm_k<<<BT, 256, 0, stream>>>(x, hb, ln1_g + (size_t)l * DD, ln1_b + (size_t)l * DD);
        gemm_bt<false, false, false><<<dim3(3 * DD / 64, BT / 64), 256, 0, stream>>>(
            hb, qkv_w + (size_t)l * 3 * DD * DD, nullptr, qkvb, BT, 3 * DD, DD);
        attn_k<<<BB * HH * TT, 256, 0, stream>>>(qkvb, hb);
        gemm_bt<true, false, false><<<dim3(DD / 64, BT / 64), 256, 0, stream>>>(
            hb, proj_w + (size_t)l * DD * DD, nullptr, x, BT, DD, DD);
        layernorm_k<<<BT, 256, 0, stream>>>(x, hb, ln2_g + (size_t)l * DD, ln2_b + (size_t)l * DD);
        gemm_bt<false, true, true><<<dim3(FFD / 64, BT / 64), 256, 0, stream>>>(
            hb, mlp_w1 + (size_t)l * FFD * DD, mlp_b1 + (size_t)l * FFD, ffb, BT, FFD, DD);
        gemm_bt<true, true, false><<<dim3(DD / 64, BT / 64), 256, 0, stream>>>(
            ffb, mlp_w2 + (size_t)l * DD * FFD, mlp_b2 + (size_t)l * DD, x, BT, DD, FFD);
    }

    layernorm_k<<<BT, 256, 0, stream>>>(x, hb, lnf_g, lnf_b);
    gemm_bt<false, false, false><<<dim3(VV / 64, BT / 64), 256, 0, stream>>>(
        hb, head_w, nullptr, out, BT, VV, DD);
}

// Round 3
// 11050.624 us; speedup vs baseline: 1.9911x; 1.9911x over previous
//
#include <hip/hip_runtime.h>
#include <hip/hip_bf16.h>
#include <math.h>

#define BB 4
#define TT 1024
#define DD 1024
#define HH 16
#define HDIM 64
#define FFD 4096
#define VV 32000
#define LL 6
#define BT (BB * TT)

typedef __bf16 bf16;
typedef bf16 bf16x8 __attribute__((ext_vector_type(8)));
typedef bf16 bf16x4 __attribute__((ext_vector_type(4)));
typedef float f32x4 __attribute__((ext_vector_type(4)));

__device__ __forceinline__ void gload16(const void* g, void* l) {
    __builtin_amdgcn_global_load_lds((__attribute__((address_space(1))) unsigned int*)(g),
                                     (__attribute__((address_space(3))) unsigned int*)(l),
                                     16, 0, 0);
}

// ---------------- embedding: x = tok_emb[idx] + pos_emb (f32) ----------------
__global__ __launch_bounds__(256) void embed_k(const int* __restrict__ idx,
                                               const float* __restrict__ tok,
                                               const float* __restrict__ pos,
                                               float* __restrict__ x) {
    int row = blockIdx.x;
    int tid = threadIdx.x;
    int t = row & (TT - 1);
    int token = idx[row];
    float4 a = *(const float4*)(tok + (size_t)token * DD + tid * 4);
    float4 p = *(const float4*)(pos + (size_t)t * DD + tid * 4);
    float4 o = make_float4(a.x + p.x, a.y + p.y, a.z + p.z, a.w + p.w);
    *(float4*)(x + (size_t)row * DD + tid * 4) = o;
}

// ---------------- f32 -> bf16 conversion (weights) ----------------
__global__ __launch_bounds__(256) void cvt_bf16_k(const float* __restrict__ in,
                                                  bf16* __restrict__ out, long n) {
    long i0 = ((long)blockIdx.x * 256 + threadIdx.x) * 8;
    long stride = (long)gridDim.x * 256 * 8;
    for (long i = i0; i < n; i += stride) {
        float4 v0 = *(const float4*)(in + i);
        float4 v1 = *(const float4*)(in + i + 4);
        bf16x8 o;
        o[0] = (bf16)v0.x; o[1] = (bf16)v0.y; o[2] = (bf16)v0.z; o[3] = (bf16)v0.w;
        o[4] = (bf16)v1.x; o[5] = (bf16)v1.y; o[6] = (bf16)v1.z; o[7] = (bf16)v1.w;
        *(bf16x8*)(out + i) = o;
    }
}

// ---------------- layernorm: f32 in, bf16 out ----------------
__global__ __launch_bounds__(256) void layernorm_k(const float* __restrict__ in,
                                                   bf16* __restrict__ out,
                                                   const float* __restrict__ g,
                                                   const float* __restrict__ b) {
    __shared__ float red[256];
    int row = blockIdx.x;
    int tid = threadIdx.x;
    const float* ip = in + (size_t)row * DD;
    float4 v = *(const float4*)(ip + tid * 4);

    float s = v.x + v.y + v.z + v.w;
    red[tid] = s; __syncthreads();
    for (int st = 128; st > 0; st >>= 1) { if (tid < st) red[tid] += red[tid + st]; __syncthreads(); }
    float mu = red[0] * (1.0f / DD);
    __syncthreads();

    float d0 = v.x - mu, d1 = v.y - mu, d2 = v.z - mu, d3 = v.w - mu;
    red[tid] = d0 * d0 + d1 * d1 + d2 * d2 + d3 * d3; __syncthreads();
    for (int st = 128; st > 0; st >>= 1) { if (tid < st) red[tid] += red[tid + st]; __syncthreads(); }
    float var = red[0] * (1.0f / DD);
    float rs = rsqrtf(var + 1e-5f);

    float4 gv = *(const float4*)(g + tid * 4);
    float4 bv = *(const float4*)(b + tid * 4);
    bf16x4 o;
    o[0] = (bf16)(d0 * rs * gv.x + bv.x);
    o[1] = (bf16)(d1 * rs * gv.y + bv.y);
    o[2] = (bf16)(d2 * rs * gv.z + bv.z);
    o[3] = (bf16)(d3 * rs * gv.w + bv.w);
    *(bf16x4*)(out + (size_t)row * DD + tid * 4) = o;
}

// ---------------- bf16 MFMA GEMM: C[M,N] (=/+=) A[M,K] * W[N,K]^T ----------------
// 128x128 tile, BK=32, 4 waves (2x2 of 64x64), 16x16x32 bf16 MFMA, f32 accum.
template <bool ADD, bool BIAS, bool GELU, bool OBF>
__global__ __launch_bounds__(256) void gemm_mfma(const bf16* __restrict__ A,
                                                 const bf16* __restrict__ W,
                                                 const float* __restrict__ bias,
                                                 void* __restrict__ Cv,
                                                 int M, int N, int K) {
    __shared__ bf16 As[128 * 32];   // [row][k], rows of 64B
    __shared__ bf16 Ws[128 * 32];
    const int tid  = threadIdx.x;
    const int wave = tid >> 6, lane = tid & 63;
    const int m0 = blockIdx.y * 128, n0 = blockIdx.x * 128;
    const int wm = (wave >> 1) * 64, wn = (wave & 1) * 64;

    // staging map: thread t -> row t/4 (+64 for pass 1), k-elems (t&3)*8..+7
    const int srow = wave * 16 + (lane >> 2);
    const int sk   = (lane & 3) * 8;
    const bf16* Ag = A + (size_t)(m0 + srow) * K + sk;
    const bf16* Wg = W + (size_t)(n0 + srow) * K + sk;
    char* lA = (char*)As + wave * 1024;
    char* lW = (char*)Ws + wave * 1024;

    const int rl = lane & 15, kg = lane >> 4;
    const bf16* Ard = As + (size_t)(wm + rl) * 32 + kg * 8;
    const bf16* Wrd = Ws + (size_t)(wn + rl) * 32 + kg * 8;

    f32x4 acc[4][4] = {};

    for (int k0 = 0; k0 < K; k0 += 32) {
        gload16(Ag + k0,                   lA);
        gload16(Ag + k0 + (size_t)64 * K,  lA + 4096);
        gload16(Wg + k0,                   lW);
        gload16(Wg + k0 + (size_t)64 * K,  lW + 4096);
        __syncthreads();
        bf16x8 a[4], b[4];
#pragma unroll
        for (int i = 0; i < 4; ++i) a[i] = *(const bf16x8*)(Ard + i * 16 * 32);
#pragma unroll
        for (int j = 0; j < 4; ++j) b[j] = *(const bf16x8*)(Wrd + j * 16 * 32);
#pragma unroll
        for (int i = 0; i < 4; ++i)
#pragma unroll
            for (int j = 0; j < 4; ++j)
                acc[i][j] = __builtin_amdgcn_mfma_f32_16x16x32_bf16(a[i], b[j], acc[i][j], 0, 0, 0);
        __syncthreads();
    }

    const int orow  = m0 + wm + (lane >> 4) * 4;
    const int ocol0 = n0 + wn + (lane & 15);
#pragma unroll
    for (int j = 0; j < 4; ++j) {
        const int col = ocol0 + j * 16;
        float bs = 0.f;
        if (BIAS) bs = bias[col];
#pragma unroll
        for (int i = 0; i < 4; ++i) {
#pragma unroll
            for (int r = 0; r < 4; ++r) {
                int row = orow + i * 16 + r;
                float v = acc[i][j][r] + bs;
                if (GELU) v = 0.5f * v * (1.0f + erff(v * 0.70710678118654752f));
                if (OBF) {
                    ((bf16*)Cv)[(size_t)row * N + col] = (bf16)v;
                } else {
                    float* p = (float*)Cv + (size_t)row * N + col;
                    if (ADD) *p += v; else *p = v;
                }
            }
        }
    }
}

// ---------------- attention: one block per (b, h, q); f32 compute, bf16 out ----------------
__global__ __launch_bounds__(256) void attn_k(const float* __restrict__ qkv,
                                              bf16* __restrict__ y) {
    __shared__ float sc[TT];
    __shared__ float qv[HDIM];
    __shared__ float red[256];
    const int bid = blockIdx.x;
    const int q = bid & (TT - 1);
    const int h = (bid >> 10) & (HH - 1);
    const int b = bid >> 14;
    const int tid = threadIdx.x;
    const size_t rstr = 3 * DD;
    const float* base = qkv + (size_t)b * TT * rstr;

    if (tid < HDIM) qv[tid] = base[(size_t)q * rstr + h * HDIM + tid];
    __syncthreads();

    const float* kp = base + DD + h * HDIM;
    for (int k = tid; k <= q; k += 256) {
        const float* kr = kp + (size_t)k * rstr;
        float s = 0.f;
#pragma unroll 8
        for (int d = 0; d < HDIM; ++d) s += qv[d] * kr[d];
        sc[k] = s * 0.125f;
    }

    float lm = -1e30f;
    for (int k = tid; k <= q; k += 256) lm = fmaxf(lm, sc[k]);
    red[tid] = lm; __syncthreads();
    for (int st = 128; st > 0; st >>= 1) { if (tid < st) red[tid] = fmaxf(red[tid], red[tid + st]); __syncthreads(); }
    float mx = red[0]; __syncthreads();

    float ls = 0.f;
    for (int k = tid; k <= q; k += 256) { float e = __expf(sc[k] - mx); sc[k] = e; ls += e; }
    red[tid] = ls; __syncthreads();
    for (int st = 128; st > 0; st >>= 1) { if (tid < st) red[tid] += red[tid + st]; __syncthreads(); }
    float inv = 1.0f / red[0]; __syncthreads();

    const int g = tid >> 6, d = tid & 63;
    const float* vp = base + 2 * DD + h * HDIM + d;
    float part = 0.f;
    for (int k = g; k <= q; k += 4) part += sc[k] * vp[(size_t)k * rstr];
    red[tid] = part; __syncthreads();
    if (tid < 64) {
        float yv = (red[d] + red[64 + d] + red[128 + d] + red[192 + d]) * inv;
        y[(size_t)(b * TT + q) * DD + h * HDIM + d] = (bf16)yv;
    }
}

// ---------------- host ----------------
extern "C" void kernel_launch(void* const* d_in, const int* in_sizes, int n_in,
                              void* d_out, int out_size, void* d_ws, size_t ws_size,
                              hipStream_t stream) {
    const int*   idx     = (const int*)d_in[0];
    const float* tok_emb = (const float*)d_in[1];
    const float* pos_emb = (const float*)d_in[2];
    const float* ln1_g   = (const float*)d_in[3];
    const float* ln1_b   = (const float*)d_in[4];
    const float* qkv_w   = (const float*)d_in[5];
    const float* proj_w  = (const float*)d_in[6];
    const float* ln2_g   = (const float*)d_in[7];
    const float* ln2_b   = (const float*)d_in[8];
    const float* mlp_w1  = (const float*)d_in[9];
    const float* mlp_b1  = (const float*)d_in[10];
    const float* mlp_w2  = (const float*)d_in[11];
    const float* mlp_b2  = (const float*)d_in[12];
    const float* lnf_g   = (const float*)d_in[13];
    const float* lnf_b   = (const float*)d_in[14];
    const float* head_w  = (const float*)d_in[15];
    float* out = (float*)d_out;

    // workspace layout (peak 137.6 MB; round-0 layout already used 144 MB safely):
    //   [0,16)MB    x    f32 residual
    //   [16,64)MB   qkvb f32
    //   [64,72)MB   h_bf bf16 (LN out)
    //   [72,80)MB   y_bf bf16 (attn out)      \ overlapped at head time by
    //   [80,112)MB  ff_bf bf16                 | hw_bf (72..137.6 MB) -- all
    //   [112,121)MB wbuf bf16 (per-GEMM W)    / dead when head GEMM runs
    char* ws = (char*)d_ws;
    float* x     = (float*)ws;
    float* qkvb  = (float*)(ws + (16ull << 20));
    bf16*  h_bf  = (bf16*)(ws + (64ull << 20));
    bf16*  y_bf  = (bf16*)(ws + (72ull << 20));
    bf16*  ff_bf = (bf16*)(ws + (80ull << 20));
    bf16*  wbuf  = (bf16*)(ws + (112ull << 20));
    bf16*  hw_bf = (bf16*)(ws + (72ull << 20));

    embed_k<<<BT, 256, 0, stream>>>(idx, tok_emb, pos_emb, x);

    for (int l = 0; l < LL; ++l) {
        layernorm_k<<<BT, 256, 0, stream>>>(x, h_bf, ln1_g + (size_t)l * DD, ln1_b + (size_t)l * DD);
        cvt_bf16_k<<<2048, 256, 0, stream>>>(qkv_w + (size_t)l * 3 * DD * DD, wbuf, (long)3 * DD * DD);
        gemm_mfma<false, false, false, false><<<dim3(3 * DD / 128, BT / 128), 256, 0, stream>>>(
            h_bf, wbuf, nullptr, qkvb, BT, 3 * DD, DD);
        attn_k<<<BB * HH * TT, 256, 0, stream>>>(qkvb, y_bf);
        cvt_bf16_k<<<2048, 256, 0, stream>>>(proj_w + (size_t)l * DD * DD, wbuf, (long)DD * DD);
        gemm_mfma<true, false, false, false><<<dim3(DD / 128, BT / 128), 256, 0, stream>>>(
            y_bf, wbuf, nullptr, x, BT, DD, DD);
        layernorm_k<<<BT, 256, 0, stream>>>(x, h_bf, ln2_g + (size_t)l * DD, ln2_b + (size_t)l * DD);
        cvt_bf16_k<<<2048, 256, 0, stream>>>(mlp_w1 + (size_t)l * FFD * DD, wbuf, (long)FFD * DD);
        gemm_mfma<false, true, true, true><<<dim3(FFD / 128, BT / 128), 256, 0, stream>>>(
            h_bf, wbuf, mlp_b1 + (size_t)l * FFD, ff_bf, BT, FFD, DD);
        cvt_bf16_k<<<2048, 256, 0, stream>>>(mlp_w2 + (size_t)l * DD * FFD, wbuf, (long)DD * FFD);
        gemm_mfma<true, true, false, false><<<dim3(DD / 128, BT / 128), 256, 0, stream>>>(
            ff_bf, wbuf, mlp_b2 + (size_t)l * DD, x, BT, DD, FFD);
    }

    layernorm_k<<<BT, 256, 0, stream>>>(x, h_bf, lnf_g, lnf_b);
    cvt_bf16_k<<<4096, 256, 0, stream>>>(head_w, hw_bf, (long)VV * DD);
    gemm_mfma<false, false, false, false><<<dim3(VV / 128, BT / 128), 256, 0, stream>>>(
        h_bf, hw_bf, nullptr, out, BT, VV, DD);
}

// Round 4
// 2801.539 us; speedup vs baseline: 7.8538x; 3.9445x over previous
//
#include <hip/hip_runtime.h>
#include <hip/hip_bf16.h>
#include <math.h>

#define BB 4
#define TT 1024
#define DD 1024
#define HH 16
#define HDIM 64
#define FFD 4096
#define VV 32000
#define LL 6
#define BT (BB * TT)

typedef __bf16 bf16;
typedef bf16 bf16x8 __attribute__((ext_vector_type(8)));
typedef bf16 bf16x4 __attribute__((ext_vector_type(4)));
typedef float f32x4 __attribute__((ext_vector_type(4)));

__device__ __forceinline__ void gload16(const void* g, void* l) {
    __builtin_amdgcn_global_load_lds((__attribute__((address_space(1))) unsigned int*)(g),
                                     (__attribute__((address_space(3))) unsigned int*)(l),
                                     16, 0, 0);
}

// ---------------- embedding ----------------
__global__ __launch_bounds__(256) void embed_k(const int* __restrict__ idx,
                                               const float* __restrict__ tok,
                                               const float* __restrict__ pos,
                                               float* __restrict__ x) {
    int row = blockIdx.x;
    int tid = threadIdx.x;
    int t = row & (TT - 1);
    int token = idx[row];
    float4 a = *(const float4*)(tok + (size_t)token * DD + tid * 4);
    float4 p = *(const float4*)(pos + (size_t)t * DD + tid * 4);
    *(float4*)(x + (size_t)row * DD + tid * 4) =
        make_float4(a.x + p.x, a.y + p.y, a.z + p.z, a.w + p.w);
}

// ---------------- f32 -> bf16 conversion (weights) ----------------
__global__ __launch_bounds__(256) void cvt_bf16_k(const float* __restrict__ in,
                                                  bf16* __restrict__ out, long n) {
    long i0 = ((long)blockIdx.x * 256 + threadIdx.x) * 8;
    long stride = (long)gridDim.x * 256 * 8;
    for (long i = i0; i < n; i += stride) {
        float4 v0 = *(const float4*)(in + i);
        float4 v1 = *(const float4*)(in + i + 4);
        bf16x8 o;
        o[0] = (bf16)v0.x; o[1] = (bf16)v0.y; o[2] = (bf16)v0.z; o[3] = (bf16)v0.w;
        o[4] = (bf16)v1.x; o[5] = (bf16)v1.y; o[6] = (bf16)v1.z; o[7] = (bf16)v1.w;
        *(bf16x8*)(out + i) = o;
    }
}

// ---------------- layernorm: f32 in, bf16 out ----------------
__global__ __launch_bounds__(256) void layernorm_k(const float* __restrict__ in,
                                                   bf16* __restrict__ out,
                                                   const float* __restrict__ g,
                                                   const float* __restrict__ b) {
    __shared__ float red[256];
    int row = blockIdx.x;
    int tid = threadIdx.x;
    const float* ip = in + (size_t)row * DD;
    float4 v = *(const float4*)(ip + tid * 4);

    float s = v.x + v.y + v.z + v.w;
    red[tid] = s; __syncthreads();
    for (int st = 128; st > 0; st >>= 1) { if (tid < st) red[tid] += red[tid + st]; __syncthreads(); }
    float mu = red[0] * (1.0f / DD);
    __syncthreads();

    float d0 = v.x - mu, d1 = v.y - mu, d2 = v.z - mu, d3 = v.w - mu;
    red[tid] = d0 * d0 + d1 * d1 + d2 * d2 + d3 * d3; __syncthreads();
    for (int st = 128; st > 0; st >>= 1) { if (tid < st) red[tid] += red[tid + st]; __syncthreads(); }
    float var = red[0] * (1.0f / DD);
    float rs = rsqrtf(var + 1e-5f);

    float4 gv = *(const float4*)(g + tid * 4);
    float4 bv = *(const float4*)(b + tid * 4);
    bf16x4 o;
    o[0] = (bf16)(d0 * rs * gv.x + bv.x);
    o[1] = (bf16)(d1 * rs * gv.y + bv.y);
    o[2] = (bf16)(d2 * rs * gv.z + bv.z);
    o[3] = (bf16)(d3 * rs * gv.w + bv.w);
    *(bf16x4*)(out + (size_t)row * DD + tid * 4) = o;
}

// ---------------- bf16 MFMA GEMM: C[M,N] (=/+=) A[M,K] * W[N,K]^T ----------------
template <bool ADD, bool BIAS, bool GELU, bool OBF>
__global__ __launch_bounds__(256) void gemm_mfma(const bf16* __restrict__ A,
                                                 const bf16* __restrict__ W,
                                                 const float* __restrict__ bias,
                                                 void* __restrict__ Cv,
                                                 int M, int N, int K) {
    __shared__ bf16 As[128 * 32];
    __shared__ bf16 Ws[128 * 32];
    const int tid  = threadIdx.x;
    const int wave = tid >> 6, lane = tid & 63;
    const int m0 = blockIdx.y * 128, n0 = blockIdx.x * 128;
    const int wm = (wave >> 1) * 64, wn = (wave & 1) * 64;

    const int srow = wave * 16 + (lane >> 2);
    const int sk   = (lane & 3) * 8;
    const bf16* Ag = A + (size_t)(m0 + srow) * K + sk;
    const bf16* Wg = W + (size_t)(n0 + srow) * K + sk;
    char* lA = (char*)As + wave * 1024;
    char* lW = (char*)Ws + wave * 1024;

    const int rl = lane & 15, kg = lane >> 4;
    const bf16* Ard = As + (size_t)(wm + rl) * 32 + kg * 8;
    const bf16* Wrd = Ws + (size_t)(wn + rl) * 32 + kg * 8;

    f32x4 acc[4][4] = {};

    for (int k0 = 0; k0 < K; k0 += 32) {
        gload16(Ag + k0,                   lA);
        gload16(Ag + k0 + (size_t)64 * K,  lA + 4096);
        gload16(Wg + k0,                   lW);
        gload16(Wg + k0 + (size_t)64 * K,  lW + 4096);
        __syncthreads();
        bf16x8 a[4], b[4];
#pragma unroll
        for (int i = 0; i < 4; ++i) a[i] = *(const bf16x8*)(Ard + i * 16 * 32);
#pragma unroll
        for (int j = 0; j < 4; ++j) b[j] = *(const bf16x8*)(Wrd + j * 16 * 32);
#pragma unroll
        for (int i = 0; i < 4; ++i)
#pragma unroll
            for (int j = 0; j < 4; ++j)
                acc[i][j] = __builtin_amdgcn_mfma_f32_16x16x32_bf16(a[i], b[j], acc[i][j], 0, 0, 0);
        __syncthreads();
    }

    const int orow  = m0 + wm + (lane >> 4) * 4;
    const int ocol0 = n0 + wn + (lane & 15);
#pragma unroll
    for (int j = 0; j < 4; ++j) {
        const int col = ocol0 + j * 16;
        float bs = 0.f;
        if (BIAS) bs = bias[col];
#pragma unroll
        for (int i = 0; i < 4; ++i) {
#pragma unroll
            for (int r = 0; r < 4; ++r) {
                int row = orow + i * 16 + r;
                float v = acc[i][j][r] + bs;
                if (GELU) v = 0.5f * v * (1.0f + erff(v * 0.70710678118654752f));
                if (OBF) {
                    ((bf16*)Cv)[(size_t)row * N + col] = (bf16)v;
                } else {
                    float* p = (float*)Cv + (size_t)row * N + col;
                    if (ADD) *p += v; else *p = v;
                }
            }
        }
    }
}

// ---------------- V transpose+swizzle prep: Vt[b,h,d,t] from qkv_bf ----------------
// Vt[(bh*64+d)*1024 + q*8 + i] = V[((q&~3)|((q&3)^sw(d)))*8 + i][d], sw(d)=(d^(d>>2))&3
__global__ __launch_bounds__(256) void vprep_k(const bf16* __restrict__ qkv,
                                               bf16* __restrict__ Vt) {
    int tid = blockIdx.x * 256 + threadIdx.x;   // B*H*64*128 = 524288
    int q  = tid & 127;
    int d  = (tid >> 7) & 63;
    int bh = tid >> 13;
    int b = bh >> 4, h = bh & 15;
    int sw = (d ^ (d >> 2)) & 3;
    int srcc = (q & ~3) | ((q & 3) ^ sw);
    const bf16* src = qkv + ((size_t)(b * TT + srcc * 8)) * 3072 + 2048 + h * 64 + d;
    bf16x8 v;
#pragma unroll
    for (int i = 0; i < 8; ++i) v[i] = src[(size_t)i * 3072];
    *(bf16x8*)(Vt + ((size_t)bh * 64 + d) * 1024 + q * 8) = v;
}

// ---------------- flash attention: block = (qtile 64, h, b), 4 waves x 16 q-rows ----------------
__global__ __launch_bounds__(256) void fattn_k(const bf16* __restrict__ qkv,
                                               const bf16* __restrict__ Vt,
                                               bf16* __restrict__ y) {
    __shared__ bf16 Ks[32 * 64];      // [k][d-chunks xor-swizzled by k&7]
    __shared__ bf16 Vs[64 * 32];      // [d][t-chunks xor-swizzled by sw(d)]
    __shared__ bf16 Ps[4 * 640];      // per-wave P tile [16 q][32 k], stride 40
    const int tid = threadIdx.x, lane = tid & 63, wave = tid >> 6;
    const int g = lane >> 4, c = lane & 15;
    const int q0 = blockIdx.x * 64;
    const int h = blockIdx.y, b = blockIdx.z;
    const size_t qbase = (size_t)b * TT * 3072;

    // Q fragments (A-frag: row=c, d-elems g*8.. within chunk)
    const int qrow = q0 + wave * 16 + c;
    const bf16* qp = qkv + qbase + (size_t)qrow * 3072 + h * 64;
    bf16x8 qf0 = *(const bf16x8*)(qp + g * 8);
    bf16x8 qf1 = *(const bf16x8*)(qp + 32 + g * 8);

    // staging addresses
    const int skrow = tid >> 3, skp = tid & 7;
    const size_t koff = qbase + 1024 + h * 64 + ((skp ^ (skrow & 7)) * 8);
    const int svd = tid >> 2, svp = tid & 3;
    const size_t vtbase = ((size_t)(b * HH + h) * 64 + svd) * 1024 + svp * 8;

    float mO[4] = {-1e30f, -1e30f, -1e30f, -1e30f};
    float lO[4] = {0.f, 0.f, 0.f, 0.f};
    f32x4 acc[4] = {};

    bf16* pw = Ps + wave * 640;
    const int kend = q0 + 64;
    const int qg0 = q0 + wave * 16 + 4 * g;

    for (int k0 = 0; k0 < kend; k0 += 32) {
        gload16(qkv + koff + (size_t)(k0 + skrow) * 3072, (char*)Ks + tid * 16);
        gload16(Vt + vtbase + k0, (char*)Vs + tid * 16);
        __syncthreads();

        // scores: S^[16q x 32k] = Q . K^T
        const int cw = c & 7;
        bf16x8 kf00 = *(const bf16x8*)(Ks + c * 64        + ((g ^ cw) * 8));
        bf16x8 kf01 = *(const bf16x8*)(Ks + c * 64        + (((4 + g) ^ cw) * 8));
        bf16x8 kf10 = *(const bf16x8*)(Ks + (16 + c) * 64 + ((g ^ cw) * 8));
        bf16x8 kf11 = *(const bf16x8*)(Ks + (16 + c) * 64 + (((4 + g) ^ cw) * 8));
        f32x4 s0 = {}, s1 = {};
        s0 = __builtin_amdgcn_mfma_f32_16x16x32_bf16(qf0, kf00, s0, 0, 0, 0);
        s0 = __builtin_amdgcn_mfma_f32_16x16x32_bf16(qf1, kf01, s0, 0, 0, 0);
        s1 = __builtin_amdgcn_mfma_f32_16x16x32_bf16(qf0, kf10, s1, 0, 0, 0);
        s1 = __builtin_amdgcn_mfma_f32_16x16x32_bf16(qf1, kf11, s1, 0, 0, 0);

        // online softmax per q-row (4 rows/lane: q = qg0 + r, k = k0 + {c, 16+c})
#pragma unroll
        for (int r = 0; r < 4; ++r) {
            float a  = s0[r] * 0.125f;
            float bv = s1[r] * 0.125f;
            int qg = qg0 + r;
            if (k0 + c > qg)      a  = -1e30f;
            if (k0 + 16 + c > qg) bv = -1e30f;
            float mt = fmaxf(a, bv);
            mt = fmaxf(mt, __shfl_xor(mt, 1));
            mt = fmaxf(mt, __shfl_xor(mt, 2));
            mt = fmaxf(mt, __shfl_xor(mt, 4));
            mt = fmaxf(mt, __shfl_xor(mt, 8));
            float mn = fmaxf(mO[r], mt);
            float sc = __expf(mO[r] - mn);
            mO[r] = mn;
            float e0 = __expf(a - mn), e1 = __expf(bv - mn);
            float rs = e0 + e1;
            rs += __shfl_xor(rs, 1);
            rs += __shfl_xor(rs, 2);
            rs += __shfl_xor(rs, 4);
            rs += __shfl_xor(rs, 8);
            lO[r] = lO[r] * sc + rs;
            acc[0][r] *= sc; acc[1][r] *= sc; acc[2][r] *= sc; acc[3][r] *= sc;
            pw[(4 * g + r) * 40 + c]      = (bf16)e0;
            pw[(4 * g + r) * 40 + 16 + c] = (bf16)e1;
        }

        // PV: Y += P . V   (A-frag of P from LDS, B-frag of V from swizzled Vs)
        bf16x8 pf = *(const bf16x8*)(pw + c * 40 + g * 8);
#pragma unroll
        for (int jb = 0; jb < 4; ++jb) {
            int d = jb * 16 + c;
            int swd = (d ^ (d >> 2)) & 3;
            bf16x8 vf = *(const bf16x8*)(Vs + d * 32 + ((g ^ swd) * 8));
            acc[jb] = __builtin_amdgcn_mfma_f32_16x16x32_bf16(pf, vf, acc[jb], 0, 0, 0);
        }
        __syncthreads();
    }

    // normalize + store
#pragma unroll
    for (int r = 0; r < 4; ++r) {
        float invl = 1.0f / lO[r];
        size_t orow = (size_t)(b * TT + qg0 + r) * DD + h * 64;
#pragma unroll
        for (int jb = 0; jb < 4; ++jb)
            y[orow + jb * 16 + c] = (bf16)(acc[jb][r] * invl);
    }
}

// ---------------- host ----------------
extern "C" void kernel_launch(void* const* d_in, const int* in_sizes, int n_in,
                              void* d_out, int out_size, void* d_ws, size_t ws_size,
                              hipStream_t stream) {
    const int*   idx     = (const int*)d_in[0];
    const float* tok_emb = (const float*)d_in[1];
    const float* pos_emb = (const float*)d_in[2];
    const float* ln1_g   = (const float*)d_in[3];
    const float* ln1_b   = (const float*)d_in[4];
    const float* qkv_w   = (const float*)d_in[5];
    const float* proj_w  = (const float*)d_in[6];
    const float* ln2_g   = (const float*)d_in[7];
    const float* ln2_b   = (const float*)d_in[8];
    const float* mlp_w1  = (const float*)d_in[9];
    const float* mlp_b1  = (const float*)d_in[10];
    const float* mlp_w2  = (const float*)d_in[11];
    const float* mlp_b2  = (const float*)d_in[12];
    const float* lnf_g   = (const float*)d_in[13];
    const float* lnf_b   = (const float*)d_in[14];
    const float* head_w  = (const float*)d_in[15];
    float* out = (float*)d_out;

    // workspace (peak 121.5 MB):
    //   [0,16)    x f32        [16,40)  qkv_bf      [40,48)  Vt
    //   [48,56)   h_bf         [56,64)  y_bf        [64,96)  ff_bf
    //   [96,104)  wbuf         head: hw_bf @ [56,121.5) overlapping dead bufs
    char* ws = (char*)d_ws;
    float* x      = (float*)ws;
    bf16*  qkv_bf = (bf16*)(ws + (16ull << 20));
    bf16*  Vt     = (bf16*)(ws + (40ull << 20));
    bf16*  h_bf   = (bf16*)(ws + (48ull << 20));
    bf16*  y_bf   = (bf16*)(ws + (56ull << 20));
    bf16*  ff_bf  = (bf16*)(ws + (64ull << 20));
    bf16*  wbuf   = (bf16*)(ws + (96ull << 20));
    bf16*  hw_bf  = (bf16*)(ws + (56ull << 20));

    embed_k<<<BT, 256, 0, stream>>>(idx, tok_emb, pos_emb, x);

    for (int l = 0; l < LL; ++l) {
        layernorm_k<<<BT, 256, 0, stream>>>(x, h_bf, ln1_g + (size_t)l * DD, ln1_b + (size_t)l * DD);
        cvt_bf16_k<<<2048, 256, 0, stream>>>(qkv_w + (size_t)l * 3 * DD * DD, wbuf, (long)3 * DD * DD);
        gemm_mfma<false, false, false, true><<<dim3(3 * DD / 128, BT / 128), 256, 0, stream>>>(
            h_bf, wbuf, nullptr, qkv_bf, BT, 3 * DD, DD);
        vprep_k<<<2048, 256, 0, stream>>>(qkv_bf, Vt);
        fattn_k<<<dim3(TT / 64, HH, BB), 256, 0, stream>>>(qkv_bf, Vt, y_bf);
        cvt_bf16_k<<<2048, 256, 0, stream>>>(proj_w + (size_t)l * DD * DD, wbuf, (long)DD * DD);
        gemm_mfma<true, false, false, false><<<dim3(DD / 128, BT / 128), 256, 0, stream>>>(
            y_bf, wbuf, nullptr, x, BT, DD, DD);
        layernorm_k<<<BT, 256, 0, stream>>>(x, h_bf, ln2_g + (size_t)l * DD, ln2_b + (size_t)l * DD);
        cvt_bf16_k<<<2048, 256, 0, stream>>>(mlp_w1 + (size_t)l * FFD * DD, wbuf, (long)FFD * DD);
        gemm_mfma<false, true, true, true><<<dim3(FFD / 128, BT / 128), 256, 0, stream>>>(
            h_bf, wbuf, mlp_b1 + (size_t)l * FFD, ff_bf, BT, FFD, DD);
        cvt_bf16_k<<<2048, 256, 0, stream>>>(mlp_w2 + (size_t)l * DD * FFD, wbuf, (long)DD * FFD);
        gemm_mfma<true, true, false, false><<<dim3(DD / 128, BT / 128), 256, 0, stream>>>(
            ff_bf, wbuf, mlp_b2 + (size_t)l * DD, x, BT, DD, FFD);
    }

    layernorm_k<<<BT, 256, 0, stream>>>(x, h_bf, lnf_g, lnf_b);
    cvt_bf16_k<<<4096, 256, 0, stream>>>(head_w, hw_bf, (long)VV * DD);
    gemm_mfma<false, false, false, false><<<dim3(VV / 128, BT / 128), 256, 0, stream>>>(
        h_bf, hw_bf, nullptr, out, BT, VV, DD);
}